// Round 12
// baseline (430.952 us; speedup 1.0000x reference)
//
#include <hip/hip_runtime.h>

// ScaleDotProduct (BERT attention) B=4 H=16 S=2048 D=64 fp32 in/out.
// bf16 MFMA flash attention, key-split waves, fixed-max softmax (m=12),
// S^T = K*Q^T so P^T (C-layout) is directly the PV B-fragment.
// Paired-tile PV: two 64-key tiles fill a FULL K=32 PV B-frag.
// R8: (256,4)/64q spills; R14: QB=32 occupancy up but 25% slower ->
//   QB=64 @ (256,3). R10: cvt_pk BANNED. R11: ones-MFMA spills.
// R15: XCD swizzle -> FETCH 152->35MB; only -2% => not memory-bound.
// R16: VALU diet (pk_fma, v_perm pack) -> only -2% => not VALU-count-bound.
//   => LATENCY-bound on the in-loop LDS round trip (gld_lds+vmcnt+ds_read).
// R17 (this): NO LDS IN MAIN LOOP. K/V are wave-private and read once ->
//   load fragments straight global->VGPR from prep-arranged layouts:
//   kb[bh][t][w][c=dchunk][lm=key] (ak0/ak1 = 2x dwordx4, 1KB/wave burst),
//   vt[bh][t][w][dt][quad][lm] (4x dwordx2, 512B/wave bursts).
//   All loads are register loads -> compiler-managed waitcnt; NO manual
//   vmcnt (R14 bug class gone), no barriers, no ds_read, no in-loop LDS.
//   V double-buffered in regs: load V[t+1] top of even t (into vreg[1]),
//   bottom of odd t (into vreg[0], after PV reads it). K double-buffered.
// Spill canary: WRITE ~41MB, FETCH ~35MB; VGPR expected ~130-160.
// MFMA 16x16x32 layouts (verified m89/m91): A[m=lane&15][k=quad*8+j],
// B[k=quad*8+j][n=lane&15], C/D: col=lane&15, row=quad*4+reg.

typedef __attribute__((ext_vector_type(8))) short short8;
typedef __attribute__((ext_vector_type(4))) float floatx4;

#define S_LEN 2048
#define D_DIM 64
#define NT    32
#define L2E   1.44269504089f
#define MFIX  12.0f

static __device__ __forceinline__ unsigned short f2b(float x) {  // RNE
  union { float f; unsigned int u; } c; c.f = x;
  return (unsigned short)((c.u + 0x7FFFu + ((c.u >> 16) & 1u)) >> 16);
}
static __device__ __forceinline__ unsigned bits(float x) {
  union { float f; unsigned u; } c; c.f = x;
  return c.u;
}

__global__ __launch_bounds__(256) void prep_kernel(
    const float* __restrict__ kin, const float* __restrict__ vin,
    unsigned short* __restrict__ kb, unsigned short* __restrict__ vt) {
  const int tid = threadIdx.x, bx = blockIdx.x;
  if (bx < 2048) {
    // V transpose: one (bh,t) 64-key x 64-d tile per block ->
    // vt[bh][t][w][dt][quad][lm] : 8B unit = V[keys w*16+quad*4+0..3][d],
    // d = dt*16+lm. Thread: kg=tid>>4 -> keys kg*4..+3 (w=kg>>2, quad=kg&3),
    // dg=tid&15 -> d dg*4..+3 (one dt, lm=(dg&3)*4+i). Reads 4x float4
    // (row-coalesced); writes 2x uint4 contiguous (32B).
    const int bh = bx >> 5, t = bx & 31;
    const int kg = tid >> 4, dg = tid & 15;
    const float* vp = vin + ((size_t)bh * S_LEN + t * 64 + kg * 4) * D_DIM + dg * 4;
    float4 f[4];
#pragma unroll
    for (int j = 0; j < 4; ++j) f[j] = *(const float4*)(vp + j * D_DIM);
    unsigned u[4];
    unsigned v[4];
#pragma unroll
    for (int i = 0; i < 4; ++i) {
      const float* ff = (const float*)&f[0];
      u[i] = (unsigned)f2b(((const float*)&f[0])[i]) |
             ((unsigned)f2b(((const float*)&f[1])[i]) << 16);
      v[i] = (unsigned)f2b(((const float*)&f[2])[i]) |
             ((unsigned)f2b(((const float*)&f[3])[i]) << 16);
      (void)ff;
    }
    unsigned short* ob = vt + (((size_t)bh * 32 + t) * 4 + (kg >> 2)) * 1024 +
                         (kg & 3) * 64 + (dg >> 2) * 256 + (dg & 3) * 16;
    uint4 q0, q1;
    q0.x = u[0]; q0.y = v[0]; q0.z = u[1]; q0.w = v[1];
    q1.x = u[2]; q1.y = v[2]; q1.z = u[3]; q1.w = v[3];
    *(uint4*)(ob) = q0;
    *(uint4*)(ob + 8) = q1;
  } else {
    // K: one (bh,t) tile per block -> kb[bh][t][w][c][lm], c = d-chunk
    // (d = c*8..+7), lm = key&15. Thread: kk=tid>>2 (key), part=tid&3
    // (d part*16..+15 -> chunks c=part*2, part*2+1). Reads 64B contiguous.
    const int b2 = bx - 2048;
    const int bh = b2 >> 5, t = b2 & 31;
    const int kk = tid >> 2, part = tid & 3;
    const float* kp = kin + ((size_t)bh * S_LEN + t * 64 + kk) * D_DIM + part * 16;
    const float4 f0 = *(const float4*)(kp);
    const float4 f1 = *(const float4*)(kp + 4);
    const float4 f2 = *(const float4*)(kp + 8);
    const float4 f3 = *(const float4*)(kp + 12);
    unsigned short* ob = kb + (((size_t)bh * 32 + t) * 4 + (kk >> 4)) * 1024 +
                         (kk & 15) * 8;
    uint4 o0, o1;
    o0.x = (unsigned)f2b(f0.x) | ((unsigned)f2b(f0.y) << 16);
    o0.y = (unsigned)f2b(f0.z) | ((unsigned)f2b(f0.w) << 16);
    o0.z = (unsigned)f2b(f1.x) | ((unsigned)f2b(f1.y) << 16);
    o0.w = (unsigned)f2b(f1.z) | ((unsigned)f2b(f1.w) << 16);
    o1.x = (unsigned)f2b(f2.x) | ((unsigned)f2b(f2.y) << 16);
    o1.y = (unsigned)f2b(f2.z) | ((unsigned)f2b(f2.w) << 16);
    o1.z = (unsigned)f2b(f3.x) | ((unsigned)f2b(f3.y) << 16);
    o1.w = (unsigned)f2b(f3.z) | ((unsigned)f2b(f3.w) << 16);
    *(uint4*)(ob + (part * 2) * 128) = o0;
    *(uint4*)(ob + (part * 2 + 1) * 128) = o1;
  }
}

union SMem {
  unsigned short Qs[64 * 64];  // pre-loop Q staging (8 KB)
  float Os[64][68];            // epilogue accumulator [q][d], padded (17.4 KB)
};

__global__ __launch_bounds__(256, 3) void flash_kernel(
    const float* __restrict__ qin, const unsigned short* __restrict__ kb,
    const unsigned short* __restrict__ vt, const float* __restrict__ mask,
    float* __restrict__ out) {
  __shared__ SMem sm;
  __shared__ float Ls[4][64];

  const int tid = threadIdx.x;
  const int w = tid >> 6, lane = tid & 63, quad = lane >> 4, lm = lane & 15;
  // XCD-aware swizzle (bijective): XCD = L%8 owns heads 8*(L%8)..8*(L%8)+7
  const int L = blockIdx.x;
  const int bh = ((L & 7) << 3) + (L >> 8);  // head 0..63
  const int bx = (L >> 3) & 31;              // q-tile 0..31
  const int b = bh >> 4;
  const int q0 = bx * 64;
  const int l7 = lm & 7;

  // ---- stage Q (bf16, *0.125 folded, swizzled) into sm.Qs ----
  {
    const int row = tid >> 2, r7 = row & 7;
    const float* qp = qin + ((size_t)(bh * S_LEN + q0 + row)) * D_DIM + (tid & 3) * 16;
#pragma unroll
    for (int h = 0; h < 2; ++h) {
      const int chunk = (tid & 3) * 2 + h;
      float4 a = *(const float4*)(qp + h * 8);
      float4 c = *(const float4*)(qp + h * 8 + 4);
      uint4 o;
      o.x = (unsigned)f2b(a.x * 0.125f) | ((unsigned)f2b(a.y * 0.125f) << 16);
      o.y = (unsigned)f2b(a.z * 0.125f) | ((unsigned)f2b(a.w * 0.125f) << 16);
      o.z = (unsigned)f2b(c.x * 0.125f) | ((unsigned)f2b(c.y * 0.125f) << 16);
      o.w = (unsigned)f2b(c.z * 0.125f) | ((unsigned)f2b(c.w * 0.125f) << 16);
      *(uint4*)&sm.Qs[row * 64 + ((chunk ^ r7) * 8)] = o;
    }
  }

  // mask row base (per-key additive mask)
  const float* mrow = mask + b * S_LEN + w * 16 + quad * 4;

  __syncthreads();  // Qs visible

  // ---- hoist Q B-frags to registers (loop-invariant) ----
  short8 bq[4][2];
#pragma unroll
  for (int qs = 0; qs < 4; ++qs) {
    bq[qs][0] = *(const short8*)&sm.Qs[(qs * 16 + lm) * 64 + ((quad ^ l7) * 8)];
    bq[qs][1] = *(const short8*)&sm.Qs[(qs * 16 + lm) * 64 + (((4 + quad) ^ l7) * 8)];
  }
  // (no second barrier: nothing writes LDS until the epilogue's ph-loop,
  //  whose first __syncthreads waits for all waves)

  // ---- direct global->reg fragment sources ----
  const size_t blkbase = (size_t)bh * (NT * 4096) + w * 1024;  // shorts
  const unsigned short* kB = kb + blkbase;
  const unsigned short* vB = vt + blkbase;
  const int koff = quad * 128 + lm * 8;  // shorts; ak1 at +512 shorts
  const int voff = quad * 64 + lm * 4;   // shorts; per dt: +dt*256

  short8 kreg[2][2];
  uint2 vreg[2][4];
  kreg[0][0] = *(const short8*)(kB + koff);
  kreg[0][1] = *(const short8*)(kB + koff + 512);
#pragma unroll
  for (int dt = 0; dt < 4; ++dt)
    vreg[0][dt] = *(const uint2*)(vB + voff + dt * 256);

  floatx4 o[4][4];  // [dt][qs]
#pragma unroll
  for (int dt = 0; dt < 4; ++dt)
#pragma unroll
    for (int qs = 0; qs < 4; ++qs) o[dt][qs] = (floatx4){0.f, 0.f, 0.f, 0.f};
  float lsum[4] = {0.f, 0.f, 0.f, 0.f};
  uint4 pb[4];  // P^T B-frags, filled over an iter pair (x,y = even; z,w = odd)

  // ---- main loop: register-resident K/V, compiler-managed waits ----
#pragma unroll 2
  for (int t = 0; t < NT; ++t) {
    // prefetch next tile K (double-buffered regs)
    if (t + 1 < NT) {
      const unsigned short* kN = kB + (size_t)(t + 1) * 4096;
      kreg[(t + 1) & 1][0] = *(const short8*)(kN + koff);
      kreg[(t + 1) & 1][1] = *(const short8*)(kN + koff + 512);
    }
    // prefetch next-tile V at TOP only on even t (target vreg[1] is dead);
    // on odd t it targets vreg[0] which PV still reads -> load at BOTTOM.
    if ((t & 1) == 0 && t + 1 < NT) {
      const unsigned short* vN = vB + (size_t)(t + 1) * 4096;
#pragma unroll
      for (int dt = 0; dt < 4; ++dt)
        vreg[1][dt] = *(const uint2*)(vN + voff + dt * 256);
    }

    // mask fold for this tile: (mask - 12) * log2e  (packed fma)
    const floatx4 ml = *(const floatx4*)(mrow + t * 64);
    const floatx4 mc = ml * (float)L2E + (-MFIX * L2E);

    const short8 ak0 = kreg[t & 1][0];
    const short8 ak1 = kreg[t & 1][1];

    // S^T strips + fixed-max softmax + pack into the pair's B-frag half
#pragma unroll
    for (int qs = 0; qs < 4; ++qs) {
      floatx4 st = (floatx4){0.f, 0.f, 0.f, 0.f};
      st = __builtin_amdgcn_mfma_f32_16x16x32_bf16(ak0, bq[qs][0], st, 0, 0, 0);
      st = __builtin_amdgcn_mfma_f32_16x16x32_bf16(ak1, bq[qs][1], st, 0, 0, 0);
      const floatx4 arg = st * (float)L2E + mc;  // v_pk_fma_f32 x2
      float p[4];
#pragma unroll
      for (int r = 0; r < 4; ++r)
        p[r] = __builtin_amdgcn_exp2f(arg[r]);
      lsum[qs] += (p[0] + p[1]) + (p[2] + p[3]);
      // round-half-up bf16 pair-pack via v_perm_b32 on +0x8000-biased bits
      const unsigned u0 = bits(p[0]) + 0x8000u;
      const unsigned u1 = bits(p[1]) + 0x8000u;
      const unsigned u2 = bits(p[2]) + 0x8000u;
      const unsigned u3 = bits(p[3]) + 0x8000u;
      const unsigned lo = __builtin_amdgcn_perm(u1, u0, 0x07060302u);
      const unsigned hi = __builtin_amdgcn_perm(u3, u2, 0x07060302u);
      if ((t & 1) == 0) { pb[qs].x = lo; pb[qs].y = hi; }
      else             { pb[qs].z = lo; pb[qs].w = hi; }
    }

    // paired PV at odd t: full K=32 — j=0..3 keys from tile t-1 (vreg[0]),
    // j=4..7 from tile t (vreg[1]). setprio: keep matrix pipe fed (T5).
    if (t & 1) {
      __builtin_amdgcn_s_setprio(1);
#pragma unroll
      for (int dt = 0; dt < 4; ++dt) {
        union { uint2 u2[2]; short8 s; } av;
        av.u2[0] = vreg[0][dt];
        av.u2[1] = vreg[1][dt];
#pragma unroll
        for (int qs = 0; qs < 4; ++qs) {
          union { uint4 u; short8 s; } bp;
          bp.u = pb[qs];
          o[dt][qs] = __builtin_amdgcn_mfma_f32_16x16x32_bf16(av.s, bp.s, o[dt][qs], 0, 0, 0);
        }
      }
      __builtin_amdgcn_s_setprio(0);
      // now vreg[0] is dead: prefetch V[t+1] (even tile) into it
      if (t + 1 < NT) {
        const unsigned short* vN = vB + (size_t)(t + 1) * 4096;
#pragma unroll
        for (int dt = 0; dt < 4; ++dt)
          vreg[0][dt] = *(const uint2*)(vN + voff + dt * 256);
      }
    }
  }

  // ---- l: reduce over quads (keys), publish per-wave partials ----
#pragma unroll
  for (int qs = 0; qs < 4; ++qs) {
    float v = lsum[qs];
    v += __shfl_xor(v, 16, 64);
    v += __shfl_xor(v, 32, 64);
    lsum[qs] = v;
  }
  if (quad == 0) {
#pragma unroll
    for (int qs = 0; qs < 4; ++qs) Ls[w][qs * 16 + lm] = lsum[qs];
  }

  // ---- O^T cross-wave reduction through Os[q][d] (aliases Qs) ----
#pragma unroll
  for (int ph = 0; ph < 4; ++ph) {
    __syncthreads();
    if (w == ph) {
#pragma unroll
      for (int dt = 0; dt < 4; ++dt)
#pragma unroll
        for (int qs = 0; qs < 4; ++qs) {
          float* dst = &sm.Os[qs * 16 + lm][dt * 16 + quad * 4];
          if (ph == 0) {
            *(floatx4*)dst = o[dt][qs];
          } else {
            floatx4 cur = *(const floatx4*)dst;
            *(floatx4*)dst = cur + o[dt][qs];
          }
        }
    }
  }
  __syncthreads();

  // ---- epilogue: /l, coalesced fp32 store ----
  {
    const int q = tid >> 2, dc = (tid & 3) * 16;
    const float l = Ls[0][q] + Ls[1][q] + Ls[2][q] + Ls[3][q];
    const float inv = 1.0f / l;
    float* outp = out + ((size_t)(bh * S_LEN + q0 + q)) * D_DIM + dc;
#pragma unroll
    for (int i = 0; i < 4; ++i) {
      floatx4 v = *(const floatx4*)&sm.Os[q][dc + i * 4];
      v *= inv;
      *(floatx4*)(outp + i * 4) = v;
    }
  }
}

extern "C" void kernel_launch(void* const* d_in, const int* in_sizes, int n_in,
                              void* d_out, int out_size, void* d_ws, size_t ws_size,
                              hipStream_t stream) {
  const float* q = (const float*)d_in[0];
  const float* k = (const float*)d_in[1];
  const float* v = (const float*)d_in[2];
  const float* mask = (const float*)d_in[3];
  float* out = (float*)d_out;

  unsigned short* kb = (unsigned short*)d_ws;                       // 16.78 MB
  unsigned short* vt = kb + (size_t)64 * S_LEN * D_DIM;             // 16.78 MB

  prep_kernel<<<4096, 256, 0, stream>>>(k, v, kb, vt);
  flash_kernel<<<2048, 256, 0, stream>>>(q, kb, vt, mask, out);
}